// Round 13
// baseline (136.035 us; speedup 1.0000x reference)
//
#include <hip/hip_runtime.h>
#include <math.h>

#define NSITE 2048

// flat output offsets (floats), reference return order
#define OFF_XOUT 0
#define OFF_AGR  (NSITE*64)                // 131072
#define OFF_POSE (OFF_AGR + NSITE*64)      // 262144
#define OFF_XP   (OFF_POSE + NSITE*128)    // 524288

// ws layout: ws_h [2048][128] floats (1 MB), then ws_meta [2048] float2 (16 KB)
#define WS_META_OFF (NSITE*128)

// guarded normalize matching ref semantics: out_c = (mu_c==0) ? 0 : mu_c/||mu||
__device__ __forceinline__ void norm2_guard(float x, float y, float* ox, float* oy) {
    const float n2  = x*x + y*y;
    const float inv = (n2 > 0.f) ? rsqrtf(n2) : 0.f;
    *ox = x*inv; *oy = y*inv;
}

// ---------------------------------------------------------------------------
// Kernel A: one wave per site; 4 sites per 256-thread block; 512 blocks.
// R7-validated VERBATIM. ~5 us.
// ---------------------------------------------------------------------------
__global__ __launch_bounds__(256) void capsA(
    const float* __restrict__ x, const float* __restrict__ a,
    const float* __restrict__ pose,
    const float* __restrict__ tg1, const float* __restrict__ lin_w,
    const float* __restrict__ lin_b, float* __restrict__ out,
    float* __restrict__ ws)
{
    const int wave = threadIdx.x >> 6, lane = threadIdx.x & 63;
    const int s  = blockIdx.x*4 + wave;
    const int b  = s >> 8, hp = (s >> 4) & 15, wp = s & 15;
    const int ci = lane & 31, p0 = lane >> 5;           // p0 in {0,1}

    __shared__ float stp[4][4][64];   // tpos per site: [wave][p][2ci+c]
    __shared__ float xps[4][32];      // pooled x-max per site

    const int base = ((b*32 + 2*hp)*32 + 2*wp)*32 + ci;
    const int i0 = base + p0*32;            // p = p0   (dh=0, dw=p0)
    const int i1 = base + 1024 + p0*32;     // p = p0+2 (dh=1, dw=p0)
    const float2 pe0 = ((const float2*)pose)[i0];
    const float2 pe1 = ((const float2*)pose)[i1];
    const float  x0  = x[i0], x1 = x[i1];
    const float  a0  = a[i0], a1 = a[i1];

    // pose pooling sum in exact reference order ((p0+p1)+p2)+p3
    const float o0x = __shfl_xor(pe0.x, 32, 64);
    const float o0y = __shfl_xor(pe0.y, 32, 64);
    const float o1x = __shfl_xor(pe1.x, 32, 64);
    const float o1y = __shfl_xor(pe1.y, 32, 64);
    const bool first = (p0 == 0);
    const float A0x = first ? pe0.x : o0x,  A1x = first ? o0x : pe0.x;
    const float A2x = first ? pe1.x : o1x,  A3x = first ? o1x : pe1.x;
    const float A0y = first ? pe0.y : o0y,  A1y = first ? o0y : pe0.y;
    const float A2y = first ? pe1.y : o1y,  A3y = first ? o1y : pe1.y;
    float mx = ((A0x + A1x) + A2x) + A3x;
    float my = ((A0y + A1y) + A2y) + A3y;

    // x max-pool, Sa, count(a != 0)
    float xm = fmaxf(x0, x1);
    xm = fmaxf(xm, __shfl_xor(xm, 32, 64));
    float sa  = a0 + a1;
    float cnt = (a0 != 0.f ? 1.f : 0.f) + (a1 != 0.f ? 1.f : 0.f);
    sa  += __shfl_xor(sa,  32, 64);
    cnt += __shfl_xor(cnt, 32, 64);
    // site totals over ci
    #pragma unroll
    for (int m = 1; m <= 16; m <<= 1) {
        sa  += __shfl_xor(sa,  m, 64);
        cnt += __shfl_xor(cnt, m, 64);
    }
    if (lane == 0) ((float2*)(ws + WS_META_OFF))[s] = make_float2(sa, cnt);
    if (p0 == 0) {
        out[OFF_XP + s*32 + ci] = xm;
        xps[wave][ci] = xm;
    }

    // guarded mean
    {
        const float n   = sqrtf(mx*mx + my*my);
        const float den = n + (n == 0.f ? 1.f : 0.f);
        mx /= den; my /= den;
    }

    // tpos = [[mx,my],[-my,mx]] @ (hh,ww); hh = dh-0.5, ww = p0-0.5
    {
        const float ww_ = (float)p0 - 0.5f;
        const float t0x = -0.5f*mx + my*ww_;    // p0   (hh=-0.5)
        const float t0y =  0.5f*my + mx*ww_;
        const float t1x =  0.5f*mx + my*ww_;    // p0+2 (hh=+0.5)
        const float t1y = -0.5f*my + mx*ww_;
        ((float2*)stp[wave][p0    ])[ci] = make_float2(t0x, t0y);
        ((float2*)stp[wave][p0 + 2])[ci] = make_float2(t1x, t1y);
    }
    __syncthreads();

    // h[p][j] = sum_m tg1[j][m]*tpos[p][m]; lane does (p0, j=ci), (p0+2, j=ci)
    {
        const float4* w4 = (const float4*)(tg1 + ci*64);
        const float4* r0 = (const float4*)stp[wave][p0];
        const float4* r1 = (const float4*)stp[wave][p0 + 2];
        float h0 = 0.f, h1 = 0.f;
        #pragma unroll
        for (int k = 0; k < 16; ++k) {
            const float4 wv = w4[k], u = r0[k], v = r1[k];
            h0 += wv.x*u.x + wv.y*u.y + wv.z*u.z + wv.w*u.w;
            h1 += wv.x*v.x + wv.y*v.y + wv.z*v.z + wv.w*v.w;
        }
        ws[s*128 + p0*32 + ci]       = h0;
        ws[s*128 + (p0 + 2)*32 + ci] = h1;
    }

    // x_out[co=lane] = lin_b + sum_ci xp[ci]*lin_w[co][ci]
    {
        float acc = lin_b[lane];
        const float4* lw = (const float4*)(lin_w + lane*32);
        const float4* xv = (const float4*)xps[wave];
        #pragma unroll
        for (int k = 0; k < 8; ++k) {
            const float4 wv = lw[k], u = xv[k];
            acc += wv.x*u.x + wv.y*u.y + wv.z*u.z + wv.w*u.w;
        }
        out[OFF_XOUT + s*64 + lane] = acc;
    }
}

// ---------------------------------------------------------------------------
// Kernel B: moment-based routing, VALU fp32 theta. Same arithmetic as the
// R2/R7/R12-validated kernel (absmax 0.0039) — DO NOT change any expression
// or reduction order (bistable fixed point at >=1 (site,co), ~1e-7 margin;
// R4/R6 evidence). Scheduling-only changes vs R12:
//   * __launch_bounds__(256, 8): request 8 waves/SIMD (VGPR 36 <= 64 budget,
//     LDS 0) — R12 ran at 50% occupancy and 72% VALUBusy; the idle issue gap
//     is latency (swizzle rounds + sincos chains) uncovered by TLP.
//   * grid dim3(8, 1024): 2 sites per wave (was 4) -> 32768 waves, 8192
//     blocks = 32/CU; shorter serial chain per wave, shorter tail.
// ---------------------------------------------------------------------------
__global__ __launch_bounds__(256, 8) void capsB(
    const float* __restrict__ a, const float* __restrict__ pose,
    const float* __restrict__ tg2, const float* __restrict__ ws,
    const float* __restrict__ alpha, const float* __restrict__ beta,
    float* __restrict__ out)
{
    const int g    = blockIdx.x;            // co-group 0..7
    const int sb   = blockIdx.y;            // site block 0..1023 (2 sites)
    const int tid  = threadIdx.x;
    const int wave = tid >> 6, lane = tid & 63;
    const int co   = g*8 + wave*2 + (lane >> 5);
    const int ci   = lane & 31;

    // cache tg2 row (32 floats) in registers -- reused for 2 sites
    float4 r[8];
    {
        const float4* rp = (const float4*)(tg2 + (co*32 + ci)*32);
        #pragma unroll
        for (int k = 0; k < 8; ++k) r[k] = rp[k];
    }
    const float alp = alpha[0];
    const float bet = beta[0] - 1.0f;
    const float2* ws_meta = (const float2*)(ws + WS_META_OFF);

    const int s0 = sb*2;
    #pragma unroll
    for (int sl = 0; sl < 2; ++sl) {
        const int s = s0 + sl;
        // theta[p] = tg2_row(co*32+ci) . h[s][p]   (h loads are wave-uniform)
        const float4* h4 = (const float4*)(ws + s*128);
        float th0 = 0.f, th1 = 0.f, th2 = 0.f, th3 = 0.f;
        #pragma unroll
        for (int k = 0; k < 8; ++k) {
            const float4 rk = r[k];
            const float4 ha = h4[k];
            const float4 hb = h4[8  + k];
            const float4 hc = h4[16 + k];
            const float4 hd = h4[24 + k];
            th0 += rk.x*ha.x + rk.y*ha.y + rk.z*ha.z + rk.w*ha.w;
            th1 += rk.x*hb.x + rk.y*hb.y + rk.z*hb.z + rk.w*hb.w;
            th2 += rk.x*hc.x + rk.y*hc.y + rk.z*hc.z + rk.w*hc.w;
            th3 += rk.x*hd.x + rk.y*hd.y + rk.z*hd.z + rk.w*hd.w;
        }
        const float th[4] = {th0, th1, th2, th3};

        const int b   = s >> 8, hpi = (s >> 4) & 15, wpi = s & 15;
        const int base = ((b*32 + 2*hpi)*32 + 2*wpi)*32 + ci;

        float Sx = 0.f, Sy = 0.f, Sxx = 0.f, Sxy = 0.f, Syy = 0.f;
        #pragma unroll
        for (int p = 0; p < 4; ++p) {
            const int idx = base + (p >> 1)*1024 + (p & 1)*32;
            const float2 pe = ((const float2*)pose)[idx];
            const float  av = a[idx];
            float sn, cs;
            __sincosf(th[p], &sn, &cs);
            const float vx = pe.x*cs - pe.y*sn;   // vote = rot(theta) @ pose
            const float vy = pe.y*cs + pe.x*sn;
            const float ax = av*vx, ay = av*vy;
            Sx += ax; Sy += ay;
            Sxx += ax*vx; Sxy += ax*vy; Syy += ay*vy;
        }
        // one butterfly over the 32 lanes of this co-half (masks 1..16)
        #pragma unroll
        for (int m = 1; m <= 16; m <<= 1) {
            Sx  += __shfl_xor(Sx,  m, 64);
            Sy  += __shfl_xor(Sy,  m, 64);
            Sxx += __shfl_xor(Sxx, m, 64);
            Sxy += __shfl_xor(Sxy, m, 64);
            Syy += __shfl_xor(Syy, m, 64);
        }

        // fixed point on moments (all lanes redundantly; stores from lane 0/32)
        float px, py;
        norm2_guard(Sx, Sy, &px, &py);            // p0 (weight = a)
        float qx = px, qy = py;
        #pragma unroll
        for (int it = 0; it < 3; ++it) {
            qx = px; qy = py;                     // ends as p2
            const float mx = Sx + px*Sxx + py*Sxy;
            const float my = Sy + px*Sxy + py*Syy;
            norm2_guard(mx, my, &px, &py);        // ends as p3
        }
        const float2 meta = ws_meta[s];           // (Sa, count(a!=0))
        const float nd_sum = 0.25f*(meta.x + (px + qx)*Sx + (py + qy)*Sy
                           + px*qx*Sxx + (px*qy + py*qx)*Sxy + py*qy*Syy);
        const float wsum = meta.y;
        const float msk  = (wsum != 0.f) ? 1.f : 0.f;
        const float nd   = nd_sum / (wsum + (1.f - msk)) * msk;
        const float z    = alp*nd + bet;
        const float agr  = msk / (1.f + __expf(-z));

        if ((lane & 31) == 0) {
            out[OFF_AGR  + s*64  + co]       = agr;
            out[OFF_POSE + s*128 + co*2]     = px;
            out[OFF_POSE + s*128 + co*2 + 1] = py;
        }
    }
}

extern "C" void kernel_launch(void* const* d_in, const int* in_sizes, int n_in,
                              void* d_out, int out_size, void* d_ws, size_t ws_size,
                              hipStream_t stream) {
    const float* x     = (const float*)d_in[0];
    const float* a     = (const float*)d_in[1];
    const float* pose  = (const float*)d_in[2];
    const float* alpha = (const float*)d_in[3];
    const float* beta  = (const float*)d_in[4];
    const float* lin_w = (const float*)d_in[5];
    const float* lin_b = (const float*)d_in[6];
    const float* tg1   = (const float*)d_in[7];
    const float* tg2   = (const float*)d_in[8];
    float* out = (float*)d_out;
    float* ws  = (float*)d_ws;   // 1 MB h + 16 KB meta

    capsA<<<NSITE/4, 256, 0, stream>>>(x, a, pose, tg1, lin_w, lin_b, out, ws);
    capsB<<<dim3(8, NSITE/2), 256, 0, stream>>>(a, pose, tg2, ws, alpha, beta, out);
}

// Round 15
// 134.212 us; speedup vs baseline: 1.0136x; 1.0136x over previous
//
#include <hip/hip_runtime.h>
#include <math.h>

#define NSITE 2048

// flat output offsets (floats), reference return order
#define OFF_XOUT 0
#define OFF_AGR  (NSITE*64)                // 131072
#define OFF_POSE (OFF_AGR + NSITE*64)      // 262144
#define OFF_XP   (OFF_POSE + NSITE*128)    // 524288

// ws layout (float indices):
//   [0,262144)        h fp32 [2048][128]           (exact path)
//   [262144,266240)   meta float2 [2048]           (Sa, cnt)
//   [266240,397312)   h_hi bf16 [2048][128] (as shorts)
//   [397312,528384)   h_lo bf16
//   [528384,659456)   h_zz bf16 (3rd split term)
//   [659456,692224)   flags uchar [2048*64]
// total 692224 floats = 2.64 MB
#define WS_META_OFF (NSITE*128)
#define WS_HHI_OFF  266240
#define WS_HLO_OFF  397312
#define WS_HZZ_OFF  528384
#define WS_FLG_OFF  659456

typedef __attribute__((ext_vector_type(8))) short bf16x8;
typedef __attribute__((ext_vector_type(4))) float f32x4;
typedef unsigned char uchar;

__device__ __forceinline__ short f2bf(float f) {
    union { float f; unsigned u; } c; c.f = f;
    const unsigned r = c.u + 0x7FFF + ((c.u >> 16) & 1);   // RNE
    return (short)(r >> 16);
}
__device__ __forceinline__ float bf2f(short h) {
    union { unsigned u; float f; } c; c.u = ((unsigned)(unsigned short)h) << 16;
    return c.f;
}
__device__ __forceinline__ void f2bf_split3(float f, short* hi, short* lo, short* ll) {
    *hi = f2bf(f);
    const float r = f - bf2f(*hi);
    *lo = f2bf(r);
    *ll = f2bf(r - bf2f(*lo));
}

// guarded normalize matching ref semantics: out_c = (mu_c==0) ? 0 : mu_c/||mu||
__device__ __forceinline__ void norm2_guard(float x, float y, float* ox, float* oy) {
    const float n2  = x*x + y*y;
    const float inv = (n2 > 0.f) ? rsqrtf(n2) : 0.f;
    *ox = x*inv; *oy = y*inv;
}
// variant tracking min ||mu||^2 for the margin flag
__device__ __forceinline__ void norm2_guard_m(float x, float y, float* ox, float* oy, float* minr2) {
    const float n2  = x*x + y*y;
    *minr2 = fminf(*minr2, n2);
    const float inv = (n2 > 0.f) ? rsqrtf(n2) : 0.f;
    *ox = x*inv; *oy = y*inv;
}

// ---------------------------------------------------------------------------
// Kernel A: one wave per site (R7-validated pipeline, arithmetic untouched).
// Adds: store h also as a 3-way bf16 split for the MFMA pass A-fragments.
// ---------------------------------------------------------------------------
__global__ __launch_bounds__(256) void capsA(
    const float* __restrict__ x, const float* __restrict__ a,
    const float* __restrict__ pose,
    const float* __restrict__ tg1, const float* __restrict__ lin_w,
    const float* __restrict__ lin_b, float* __restrict__ out,
    float* __restrict__ ws)
{
    const int wave = threadIdx.x >> 6, lane = threadIdx.x & 63;
    const int s  = blockIdx.x*4 + wave;
    const int b  = s >> 8, hp = (s >> 4) & 15, wp = s & 15;
    const int ci = lane & 31, p0 = lane >> 5;           // p0 in {0,1}

    __shared__ float stp[4][4][64];
    __shared__ float xps[4][32];

    const int base = ((b*32 + 2*hp)*32 + 2*wp)*32 + ci;
    const int i0 = base + p0*32;
    const int i1 = base + 1024 + p0*32;
    const float2 pe0 = ((const float2*)pose)[i0];
    const float2 pe1 = ((const float2*)pose)[i1];
    const float  x0  = x[i0], x1 = x[i1];
    const float  a0  = a[i0], a1 = a[i1];

    // pose pooling sum in exact reference order ((p0+p1)+p2)+p3
    const float o0x = __shfl_xor(pe0.x, 32, 64);
    const float o0y = __shfl_xor(pe0.y, 32, 64);
    const float o1x = __shfl_xor(pe1.x, 32, 64);
    const float o1y = __shfl_xor(pe1.y, 32, 64);
    const bool first = (p0 == 0);
    const float A0x = first ? pe0.x : o0x,  A1x = first ? o0x : pe0.x;
    const float A2x = first ? pe1.x : o1x,  A3x = first ? o1x : pe1.x;
    const float A0y = first ? pe0.y : o0y,  A1y = first ? o0y : pe0.y;
    const float A2y = first ? pe1.y : o1y,  A3y = first ? o1y : pe1.y;
    float mx = ((A0x + A1x) + A2x) + A3x;
    float my = ((A0y + A1y) + A2y) + A3y;

    float xm = fmaxf(x0, x1);
    xm = fmaxf(xm, __shfl_xor(xm, 32, 64));
    float sa  = a0 + a1;
    float cnt = (a0 != 0.f ? 1.f : 0.f) + (a1 != 0.f ? 1.f : 0.f);
    sa  += __shfl_xor(sa,  32, 64);
    cnt += __shfl_xor(cnt, 32, 64);
    #pragma unroll
    for (int m = 1; m <= 16; m <<= 1) {
        sa  += __shfl_xor(sa,  m, 64);
        cnt += __shfl_xor(cnt, m, 64);
    }
    if (lane == 0) ((float2*)(ws + WS_META_OFF))[s] = make_float2(sa, cnt);
    if (p0 == 0) {
        out[OFF_XP + s*32 + ci] = xm;
        xps[wave][ci] = xm;
    }

    {
        const float n   = sqrtf(mx*mx + my*my);
        const float den = n + (n == 0.f ? 1.f : 0.f);
        mx /= den; my /= den;
    }
    {
        const float ww_ = (float)p0 - 0.5f;
        const float t0x = -0.5f*mx + my*ww_;
        const float t0y =  0.5f*my + mx*ww_;
        const float t1x =  0.5f*mx + my*ww_;
        const float t1y = -0.5f*my + mx*ww_;
        ((float2*)stp[wave][p0    ])[ci] = make_float2(t0x, t0y);
        ((float2*)stp[wave][p0 + 2])[ci] = make_float2(t1x, t1y);
    }
    __syncthreads();

    {
        const float4* w4 = (const float4*)(tg1 + ci*64);
        const float4* r0 = (const float4*)stp[wave][p0];
        const float4* r1 = (const float4*)stp[wave][p0 + 2];
        float h0 = 0.f, h1 = 0.f;
        #pragma unroll
        for (int k = 0; k < 16; ++k) {
            const float4 wv = w4[k], u = r0[k], v = r1[k];
            h0 += wv.x*u.x + wv.y*u.y + wv.z*u.z + wv.w*u.w;
            h1 += wv.x*v.x + wv.y*v.y + wv.z*v.z + wv.w*v.w;
        }
        ws[s*128 + p0*32 + ci]       = h0;
        ws[s*128 + (p0 + 2)*32 + ci] = h1;
        // bf16 3-way split for the MFMA pass
        short* hhi = (short*)(ws + WS_HHI_OFF);
        short* hlo = (short*)(ws + WS_HLO_OFF);
        short* hzz = (short*)(ws + WS_HZZ_OFF);
        short h0h, h0l, h0z, h1h, h1l, h1z;
        f2bf_split3(h0, &h0h, &h0l, &h0z);
        f2bf_split3(h1, &h1h, &h1l, &h1z);
        const int e0 = s*128 + p0*32 + ci;
        const int e1 = s*128 + (p0 + 2)*32 + ci;
        hhi[e0] = h0h; hhi[e1] = h1h;
        hlo[e0] = h0l; hlo[e1] = h1l;
        hzz[e0] = h0z; hzz[e1] = h1z;
    }

    {
        float acc = lin_b[lane];
        const float4* lw = (const float4*)(lin_w + lane*32);
        const float4* xv = (const float4*)xps[wave];
        #pragma unroll
        for (int k = 0; k < 8; ++k) {
            const float4 wv = lw[k], u = xv[k];
            acc += wv.x*u.x + wv.y*u.y + wv.z*u.z + wv.w*u.w;
        }
        out[OFF_XOUT + s*64 + lane] = acc;
    }
}

// ---------------------------------------------------------------------------
// Pass 1: MFMA theta (A 3-way x B 3-way, 6 terms kept per half -> dtheta
// ~3e-8, vs 5e-6 in R14 which missed threshold by 0.3%) + moment routing for
// ALL pairs, tracking min ||mu||^2; flags pairs with ||mu|| < 0.05*Sa for
// exact recomputation (R14 evidence: this flag catches ALL bistable pairs —
// max unflagged error was linear-amplification 0.0996, no 0.164 flips).
// Wave tile: M=16 (4 sites x 4 p) x N=32 (one co), K=32.
// ---------------------------------------------------------------------------
__global__ __launch_bounds__(256) void capsB_m(
    const float* __restrict__ a, const float* __restrict__ pose,
    const float* __restrict__ tg2, float* __restrict__ ws,
    const float* __restrict__ alpha, const float* __restrict__ beta,
    float* __restrict__ out)
{
    const int co   = blockIdx.x;
    const int tid  = threadIdx.x;
    const int wave = tid >> 6, lane = tid & 63;
    const int q    = lane >> 4;
    const int n    = lane & 15;

    // B fragments, 3-way split (once per wave)
    bf16x8 b0h, b0l, b0z, b1h, b1l, b1z;
    {
        const float* r0 = tg2 + (co*32 + n)*32 + q*8;
        const float* r1 = r0 + 512;
        #pragma unroll
        for (int j = 0; j < 8; ++j) {
            short h, l, z;
            f2bf_split3(r0[j], &h, &l, &z); b0h[j] = h; b0l[j] = l; b0z[j] = z;
            f2bf_split3(r1[j], &h, &l, &z); b1h[j] = h; b1l[j] = l; b1z[j] = z;
        }
    }
    const short* hhi = (const short*)(ws + WS_HHI_OFF);
    const short* hlo = (const short*)(ws + WS_HLO_OFF);
    const short* hzz = (const short*)(ws + WS_HZZ_OFF);
    uchar* flags = (uchar*)(ws + WS_FLG_OFF);
    const float alp = alpha[0];
    const float bet = beta[0] - 1.0f;
    const float2* ws_meta = (const float2*)(ws + WS_META_OFF);

    #pragma unroll
    for (int it = 0; it < 4; ++it) {
        const int s0 = (((blockIdx.y*4 + wave)*4) + it)*4;

        const int aoff = (s0 + (n >> 2))*128 + (n & 3)*32 + q*8;
        const bf16x8 ah = *(const bf16x8*)(hhi + aoff);
        const bf16x8 al = *(const bf16x8*)(hlo + aoff);
        const bf16x8 az = *(const bf16x8*)(hzz + aoff);

        f32x4 c0 = {0.f, 0.f, 0.f, 0.f};
        f32x4 c1 = {0.f, 0.f, 0.f, 0.f};
        // smallest terms first
        c0 = __builtin_amdgcn_mfma_f32_16x16x32_bf16(az, b0h, c0, 0, 0, 0);
        c0 = __builtin_amdgcn_mfma_f32_16x16x32_bf16(ah, b0z, c0, 0, 0, 0);
        c0 = __builtin_amdgcn_mfma_f32_16x16x32_bf16(al, b0l, c0, 0, 0, 0);
        c0 = __builtin_amdgcn_mfma_f32_16x16x32_bf16(al, b0h, c0, 0, 0, 0);
        c0 = __builtin_amdgcn_mfma_f32_16x16x32_bf16(ah, b0l, c0, 0, 0, 0);
        c0 = __builtin_amdgcn_mfma_f32_16x16x32_bf16(ah, b0h, c0, 0, 0, 0);
        c1 = __builtin_amdgcn_mfma_f32_16x16x32_bf16(az, b1h, c1, 0, 0, 0);
        c1 = __builtin_amdgcn_mfma_f32_16x16x32_bf16(ah, b1z, c1, 0, 0, 0);
        c1 = __builtin_amdgcn_mfma_f32_16x16x32_bf16(al, b1l, c1, 0, 0, 0);
        c1 = __builtin_amdgcn_mfma_f32_16x16x32_bf16(al, b1h, c1, 0, 0, 0);
        c1 = __builtin_amdgcn_mfma_f32_16x16x32_bf16(ah, b1l, c1, 0, 0, 0);
        c1 = __builtin_amdgcn_mfma_f32_16x16x32_bf16(ah, b1h, c1, 0, 0, 0);

        const int site = s0 + q;
        const int b    = site >> 8, hpi = (site >> 4) & 15, wpi = site & 15;
        const int base = ((b*32 + 2*hpi)*32 + 2*wpi)*32;

        float Sx = 0.f, Sy = 0.f, Sxx = 0.f, Sxy = 0.f, Syy = 0.f;
        #pragma unroll
        for (int p = 0; p < 4; ++p) {
            const int idx0 = base + (p >> 1)*1024 + (p & 1)*32 + n;
            const int idx1 = idx0 + 16;
            const float2 pe0 = ((const float2*)pose)[idx0];
            const float2 pe1 = ((const float2*)pose)[idx1];
            const float  a0  = a[idx0];
            const float  a1  = a[idx1];
            float s0n, c0n, s1n, c1n;
            __sincosf(c0[p], &s0n, &c0n);
            __sincosf(c1[p], &s1n, &c1n);
            const float v0x = pe0.x*c0n - pe0.y*s0n;
            const float v0y = pe0.y*c0n + pe0.x*s0n;
            const float v1x = pe1.x*c1n - pe1.y*s1n;
            const float v1y = pe1.y*c1n + pe1.x*s1n;
            const float a0x = a0*v0x, a0y = a0*v0y;
            const float a1x = a1*v1x, a1y = a1*v1y;
            Sx  += a0x + a1x;
            Sy  += a0y + a1y;
            Sxx += a0x*v0x + a1x*v1x;
            Sxy += a0x*v0y + a1x*v1y;
            Syy += a0y*v0y + a1y*v1y;
        }
        #pragma unroll
        for (int m = 1; m <= 8; m <<= 1) {
            Sx  += __shfl_xor(Sx,  m, 64);
            Sy  += __shfl_xor(Sy,  m, 64);
            Sxx += __shfl_xor(Sxx, m, 64);
            Sxy += __shfl_xor(Sxy, m, 64);
            Syy += __shfl_xor(Syy, m, 64);
        }

        float minr2 = 3.4e38f;
        float px, py;
        norm2_guard_m(Sx, Sy, &px, &py, &minr2);
        float qx = px, qy = py;
        #pragma unroll
        for (int it2 = 0; it2 < 3; ++it2) {
            qx = px; qy = py;
            const float mx = Sx + px*Sxx + py*Sxy;
            const float my = Sy + px*Sxy + py*Syy;
            norm2_guard_m(mx, my, &px, &py, &minr2);
        }
        const float2 meta = ws_meta[site];
        const float nd_sum = 0.25f*(meta.x + (px + qx)*Sx + (py + qy)*Sy
                           + px*qx*Sxx + (px*qy + py*qx)*Sxy + py*qy*Syy);
        const float wsum = meta.y;
        const float msk  = (wsum != 0.f) ? 1.f : 0.f;
        const float nd   = nd_sum / (wsum + (1.f - msk)) * msk;
        const float z    = alp*nd + bet;
        const float agr  = msk / (1.f + __expf(-z));
        // margin flag: ||mu|| < 0.05 * Sa
        const int fl = (minr2 < 2.5e-3f*(meta.x*meta.x)) ? 1 : 0;

        if (n == 0) {
            out[OFF_AGR  + site*64  + co]       = agr;
            out[OFF_POSE + site*128 + co*2]     = px;
            out[OFF_POSE + site*128 + co*2 + 1] = py;
            flags[site*64 + co] = (uchar)fl;
        }
    }
}

// ---------------------------------------------------------------------------
// Pass 2: exact fixup. Grid (8, 2048): one site per wave; early-exit unless
// some lane's (site,co) is flagged; otherwise run the R13-validated routing
// VERBATIM (bit-identical to the 0.0039 pass) and overwrite.
// ---------------------------------------------------------------------------
__global__ __launch_bounds__(256) void capsB_fix(
    const float* __restrict__ a, const float* __restrict__ pose,
    const float* __restrict__ tg2, const float* __restrict__ ws,
    const float* __restrict__ alpha, const float* __restrict__ beta,
    float* __restrict__ out)
{
    const int g    = blockIdx.x;
    const int s    = blockIdx.y;            // one site per wave
    const int tid  = threadIdx.x;
    const int wave = tid >> 6, lane = tid & 63;
    const int co   = g*8 + wave*2 + (lane >> 5);
    const int ci   = lane & 31;

    const uchar* flags = (const uchar*)(ws + WS_FLG_OFF);
    const bool need = flags[s*64 + co] != 0;
    if (__ballot(need) == 0ULL) return;

    float4 r[8];
    {
        const float4* rp = (const float4*)(tg2 + (co*32 + ci)*32);
        #pragma unroll
        for (int k = 0; k < 8; ++k) r[k] = rp[k];
    }
    const float alp = alpha[0];
    const float bet = beta[0] - 1.0f;
    const float2* ws_meta = (const float2*)(ws + WS_META_OFF);

    const float4* h4 = (const float4*)(ws + s*128);
    float th0 = 0.f, th1 = 0.f, th2 = 0.f, th3 = 0.f;
    #pragma unroll
    for (int k = 0; k < 8; ++k) {
        const float4 rk = r[k];
        const float4 ha = h4[k];
        const float4 hb = h4[8  + k];
        const float4 hc = h4[16 + k];
        const float4 hd = h4[24 + k];
        th0 += rk.x*ha.x + rk.y*ha.y + rk.z*ha.z + rk.w*ha.w;
        th1 += rk.x*hb.x + rk.y*hb.y + rk.z*hb.z + rk.w*hb.w;
        th2 += rk.x*hc.x + rk.y*hc.y + rk.z*hc.z + rk.w*hc.w;
        th3 += rk.x*hd.x + rk.y*hd.y + rk.z*hd.z + rk.w*hd.w;
    }
    const float th[4] = {th0, th1, th2, th3};

    const int b   = s >> 8, hpi = (s >> 4) & 15, wpi = s & 15;
    const int base = ((b*32 + 2*hpi)*32 + 2*wpi)*32 + ci;

    float Sx = 0.f, Sy = 0.f, Sxx = 0.f, Sxy = 0.f, Syy = 0.f;
    #pragma unroll
    for (int p = 0; p < 4; ++p) {
        const int idx = base + (p >> 1)*1024 + (p & 1)*32;
        const float2 pe = ((const float2*)pose)[idx];
        const float  av = a[idx];
        float sn, cs;
        __sincosf(th[p], &sn, &cs);
        const float vx = pe.x*cs - pe.y*sn;
        const float vy = pe.y*cs + pe.x*sn;
        const float ax = av*vx, ay = av*vy;
        Sx += ax; Sy += ay;
        Sxx += ax*vx; Sxy += ax*vy; Syy += ay*vy;
    }
    #pragma unroll
    for (int m = 1; m <= 16; m <<= 1) {
        Sx  += __shfl_xor(Sx,  m, 64);
        Sy  += __shfl_xor(Sy,  m, 64);
        Sxx += __shfl_xor(Sxx, m, 64);
        Sxy += __shfl_xor(Sxy, m, 64);
        Syy += __shfl_xor(Syy, m, 64);
    }

    float px, py;
    norm2_guard(Sx, Sy, &px, &py);
    float qx = px, qy = py;
    #pragma unroll
    for (int it = 0; it < 3; ++it) {
        qx = px; qy = py;
        const float mx = Sx + px*Sxx + py*Sxy;
        const float my = Sy + px*Sxy + py*Syy;
        norm2_guard(mx, my, &px, &py);
    }
    const float2 meta = ws_meta[s];
    const float nd_sum = 0.25f*(meta.x + (px + qx)*Sx + (py + qy)*Sy
                       + px*qx*Sxx + (px*qy + py*qx)*Sxy + py*qy*Syy);
    const float wsum = meta.y;
    const float msk  = (wsum != 0.f) ? 1.f : 0.f;
    const float nd   = nd_sum / (wsum + (1.f - msk)) * msk;
    const float z    = alp*nd + bet;
    const float agr  = msk / (1.f + __expf(-z));

    if ((lane & 31) == 0) {
        out[OFF_AGR  + s*64  + co]       = agr;
        out[OFF_POSE + s*128 + co*2]     = px;
        out[OFF_POSE + s*128 + co*2 + 1] = py;
    }
}

extern "C" void kernel_launch(void* const* d_in, const int* in_sizes, int n_in,
                              void* d_out, int out_size, void* d_ws, size_t ws_size,
                              hipStream_t stream) {
    const float* x     = (const float*)d_in[0];
    const float* a     = (const float*)d_in[1];
    const float* pose  = (const float*)d_in[2];
    const float* alpha = (const float*)d_in[3];
    const float* beta  = (const float*)d_in[4];
    const float* lin_w = (const float*)d_in[5];
    const float* lin_b = (const float*)d_in[6];
    const float* tg1   = (const float*)d_in[7];
    const float* tg2   = (const float*)d_in[8];
    float* out = (float*)d_out;
    float* ws  = (float*)d_ws;   // 2.64 MB used

    capsA<<<NSITE/4, 256, 0, stream>>>(x, a, pose, tg1, lin_w, lin_b, out, ws);
    capsB_m<<<dim3(64, 32), 256, 0, stream>>>(a, pose, tg2, ws, alpha, beta, out);
    capsB_fix<<<dim3(8, NSITE), 256, 0, stream>>>(a, pose, tg2, ws, alpha, beta, out);
}